// Round 16
// baseline (64.670 us; speedup 1.0000x reference)
//
#include <hip/hip_runtime.h>

#define B_ 4
#define H_ 12
#define N_ 1028
#define D_ 64
#define R_ 4
#define L_ 3969
#define HID_ 32
#define KBLK 64
#define NT_ 17
#define NBH_ 48
#define QBLK 64
#define NQT 17             // q-tiles of 64
#define NWG (NBH_*NQT)     // 816 = 8*102
#define TBL 3973           // per-h bias table: 4 zero-sentinels + 3969
#define MUKP 1088          // padded muk row
#define LOG2E 1.4426950408889634f
#define SCL1 (0.125f*LOG2E)

typedef __attribute__((ext_vector_type(8)))  short bf16x8;
typedef __attribute__((ext_vector_type(4)))  float f32x4;
typedef __attribute__((ext_vector_type(4), aligned(4))) float f32x4u;  // 4B-aligned quad
typedef __attribute__((ext_vector_type(2)))  unsigned int u32x2;
typedef __attribute__((ext_vector_type(4)))  unsigned int u32x4;
typedef __attribute__((address_space(3))) unsigned int lds_u32;
typedef const __attribute__((address_space(1))) unsigned int glb_u32;

__device__ __forceinline__ unsigned pkbf(float lo, float hi) {
  unsigned r;
  asm("v_cvt_pk_bf16_f32 %0, %1, %2" : "=v"(r) : "v"(lo), "v"(hi));
  return r;
}
__device__ __forceinline__ float exp2_fast(float x) {
  float r; asm("v_exp_f32 %0, %1" : "=v"(r) : "v"(x)); return r;
}
__device__ __forceinline__ float sgnlog1p(float x) {
  float t = log1pf(fabsf(x));
  return (x > 0.f) ? t : ((x < 0.f) ? -t : 0.f);
}

// ---- fused prep (r14/r15-proven): bias tables + K/V' pi-images + raw mut ----
// V' image in PV pi-order: within a 32-kc half, kc_loc -> p = 8*((kc_loc>>2)&3)
// + (kc_loc&3) + 4*(kc_loc>>4) so S^T output regs ARE the PV B-operand.
__global__ __launch_bounds__(256) void prep_kernel(
    const float* __restrict__ rel, const float* __restrict__ W1,
    const float* __restrict__ b1, const float* __restrict__ W2,
    const float* __restrict__ gammag, const float* __restrict__ kg,
    const float* __restrict__ vg, const float* __restrict__ mug,
    float* __restrict__ btgf, float* __restrict__ mut,
    unsigned short* __restrict__ kv)
{
  const int blk = blockIdx.x, tid = threadIdx.x;
  if (blk < 16) {
    if (blk == 0 && tid < 48) btgf[(tid >> 2)*TBL + (tid & 3)] = 0.f;
    int l = blk*256 + tid;
    if (l < L_) {
      float r0 = rel[2*l], r1 = rel[2*l+1];
      float hid[HID_];
#pragma unroll
      for (int j = 0; j < HID_; ++j) {
        float x = W1[2*j]*r0 + W1[2*j+1]*r1 + b1[j];
        hid[j] = 0.5f * x * (1.f + erff(x * 0.70710678118654752f));
      }
#pragma unroll
      for (int h = 0; h < H_; ++h) {
        float acc = 0.f;
#pragma unroll
        for (int j = 0; j < HID_; ++j) acc += W2[h*HID_+j]*hid[j];
        float gscl = LOG2E / (1.f + __expf(-gammag[h]));
        btgf[h*TBL + 4 + l] = gscl * acc;
      }
    }
  } else if (blk < 16 + NBH_*NT_) {
    const int idx = blk - 16;
    const int bh = idx / NT_, t = idx - bh*NT_;
    const int k0 = t * KBLK;
    const float* kb = kg + (size_t)bh*N_*D_;
    const float* vb = vg + (size_t)bh*N_*D_;
    unsigned short* Ko = kv + (size_t)idx*8192;
    unsigned short* Vo = Ko + 4096;
    // K image [kc][d ^ swz]
    const int kcb = tid >> 4, d4 = (tid & 15)*4;
#pragma unroll
    for (int i = 0; i < 4; ++i) {
      int kc = kcb + i*16;
      int kr = k0 + kc; if (kr >= N_) kr = N_-1;
      f32x4 a = *(const f32x4*)(kb + (size_t)kr*D_ + d4);
      *(u32x2*)&Ko[kc*64 + (d4 ^ ((kc & 7) << 3))] = (u32x2){pkbf(a[0],a[1]), pkbf(a[2],a[3])};
    }
    // V' image [d][pi(kc) ^ swz]
    const int vd0 = (tid >> 4)*4, vkc0 = (tid & 15)*4;
    const int loc = vkc0 & 31;
    const int p0 = 32*(vkc0 >> 5) + 8*((loc >> 2) & 3) + 4*(loc >> 4); // 4 contiguous
    f32x4 r[4];
#pragma unroll
    for (int i = 0; i < 4; ++i) {
      int kr = k0 + vkc0 + i; if (kr >= N_) kr = N_-1;
      r[i] = *(const f32x4*)(vb + (size_t)kr*D_ + vd0);
    }
#pragma unroll
    for (int j = 0; j < 4; ++j) {
      int d = vd0 + j;
      int addr = d*64 + ((p0 & 56) ^ ((d & 7) << 3)) + (p0 & 7);
      *(u32x2*)&Vo[addr] = (u32x2){pkbf(r[0][j],r[1][j]), pkbf(r[2][j],r[3][j])};
    }
  } else {
    int idx = (blk - (16 + NBH_*NT_))*256 + tid;
    if (idx < NBH_*N_) {
      int bh = idx / N_, n = idx - bh*N_;
      int b = bh / H_, h = bh - b*H_;
      mut[idx] = sgnlog1p(mug[((size_t)b*2*H_ + H_ + h)*N_ + n]);
    }
  }
}

// ---- attn: r15 datapath + in-block K-split (2 pipes x 4 q-waves, LDS merge) ----
// S^T = mfma(A=K,B=Q): D col=lane&15=q, row=4g+reg. [m89]  P in regs (pi map);
// O^T = mfma(A=V',B=P): col=q -> softmax fully lane-local.
// Pipe wp handles tiles {0..8 | 9..16}; partials merged via LDS at the end
// (r13-proven, zero global partial traffic).
// Register-neutral swap vs r15: mu_k now LDS (muks), bias now global preloaded
// quads issued BEFORE next-tile glds (vmcnt FIFO leaves glds in flight).
// (512,4): r6/r15-proven cap ~64 VGPR; r15 measured 48. Watch WRITE for spill.
__global__ __launch_bounds__(512, 4) void attn_kernel(
    const float* __restrict__ qg, const float* __restrict__ mug,
    const float* __restrict__ btgf, const float* __restrict__ mut,
    const unsigned short* __restrict__ kv, float* __restrict__ outg)
{
  __shared__ __align__(16) unsigned short KV[2][2][8192]; // [pipe][dbuf]: K 8KB | V' 8KB
  __shared__ __align__(16) float muks[MUKP];              // 4.35 KB; total 68.4 KB -> 2 blk/CU

  const int tid = threadIdx.x;
  const int w = tid >> 6, lane = tid & 63, g = lane >> 4, c = lane & 15;
  const int wp = w >> 2;          // k-pipeline (0: tiles 0..8, 1: tiles 9..16)
  const int wq = w & 3;           // q-group (16 rows each)

  const int orig = blockIdx.x;
  const int wg = (orig & 7)*(NWG/8) + (orig >> 3);   // bijective: 816 % 8 == 0
  const int bh = wg / NQT;
  const int qt = wg - bh*NQT;
  const int b = bh / H_, h = bh - b*H_;
  const int q0 = qt * QBLK;

  const float* qb = qg + (size_t)bh*N_*D_;
  const float* bth = btgf + h*TBL;
  const unsigned short* kvb = kv + (size_t)bh*NT_*8192;

  // per-block LDS fill (once): transformed mu_k, padded
  {
    const float* mt = mut + (size_t)bh*N_;
    for (int i = tid; i < MUKP; i += 512) muks[i] = mt[i < N_ ? i : N_-1];
  }

  // Q fragments (0.125*log2e folded): qf[ch] = Q[qrow][ch*32 + 8g .. +7]
  const int qrow = q0 + 16*wq + c;
  const int qrc = qrow < N_ ? qrow : N_-1;
  bf16x8 qf[2];
#pragma unroll
  for (int ch = 0; ch < 2; ++ch) {
    const float* p = qb + (size_t)qrc*D_ + ch*32 + 8*g;
    f32x4 a0 = *(const f32x4*)p;
    f32x4 a1 = *(const f32x4*)(p + 4);
    u32x4 qw;
    qw[0] = pkbf(a0[0]*SCL1, a0[1]*SCL1); qw[1] = pkbf(a0[2]*SCL1, a0[3]*SCL1);
    qw[2] = pkbf(a1[0]*SCL1, a1[1]*SCL1); qw[3] = pkbf(a1[2]*SCL1, a1[3]*SCL1);
    qf[ch] = __builtin_bit_cast(bf16x8, qw);
  }
  const float muq_c = (qrow < N_) ? sgnlog1p(mug[((size_t)b*2*H_ + h)*N_ + qrow]) : 0.f;
  const int qi = qrow - R_;
  const bool qok = (qi >= 0) && (qrow < N_);
  const int qy = qi >> 5, qx = qi & 31;
  const int lqc = qy*63 + qx + 1988;    // +4 sentinel +1984 geometry

  const int tbeg   = wp ? 9 : 0;
  const int tcount = wp ? 8 : 9;

  // staging: pipe wp's 4 waves copy its 16KB tile (4KB/wave, 4x1KB glds)
  auto issue = [&](int tt, int pp) {
    const char* src = (const char*)(kvb + (size_t)tt*8192) + wq*4096;
    char* dst = (char*)&KV[wp][pp][0] + wq*4096;
#pragma unroll
    for (int j = 0; j < 4; ++j) {
      int o = j*1024;
      __builtin_amdgcn_global_load_lds((glb_u32*)(src + o + lane*16),
                                       (lds_u32*)(dst + o), 16, 0, 0);
    }
  };

  float mrun = -3.0e38f, lrun = 0.f;
  f32x4 O[4];
#pragma unroll
  for (int dt = 0; dt < 4; ++dt) O[dt] = (f32x4){0.f,0.f,0.f,0.f};

  issue(tbeg, 0);

  for (int i = 0; i < 9; ++i) {
    const bool act = i < tcount;
    const int t = tbeg + i;
    const int k0 = t * KBLK;
    const int p = i & 1;

    asm volatile("s_waitcnt vmcnt(0)" ::: "memory");   // this tile's glds landed
    __syncthreads();

    // ---- bias quads (L1-hot global), BEFORE next glds (vmcnt FIFO) ----
    f32x4 bvq[4];
    if (act) {
#pragma unroll
      for (int kt = 0; kt < 4; ++kt) {
        int ki0 = k0 + kt*16 + 4*g - R_;
        int lk = (ki0 >> 5)*63 + (ki0 & 31);
        int va = lqc - lk;
        bool okq = ((unsigned)ki0 < 1024u) && qok;
        int basep = okq ? va : 3;                      // invalid -> zero sentinels
        bvq[kt] = *(const f32x4u*)(bth + (basep - 3)); // bv[3-r] = bias of r
      }
    }
    __builtin_amdgcn_sched_barrier(0);
    if (i + 1 < tcount) issue(t + 1, p ^ 1);           // flies across compute

    if (act) {
      const unsigned short* Kl = &KV[wp][p][0];
      const unsigned short* Vl = &KV[wp][p][4096];

      // ---- S^T: 4 kc-subtiles x 2 d-chunks ----
      f32x4 sc[4];
#pragma unroll
      for (int kt = 0; kt < 4; ++kt) {
        int row = kt*16 + c;
        int sw = (row & 7) << 3;
        bf16x8 ka0 = *(const bf16x8*)&Kl[row*64 + ((8*g) ^ sw)];
        bf16x8 ka1 = *(const bf16x8*)&Kl[row*64 + ((32 + 8*g) ^ sw)];
        f32x4 s = (f32x4){0.f,0.f,0.f,0.f};
        s = __builtin_amdgcn_mfma_f32_16x16x32_bf16(ka0, qf[0], s, 0, 0, 0);
        s = __builtin_amdgcn_mfma_f32_16x16x32_bf16(ka1, qf[1], s, 0, 0, 0);
        sc[kt] = s;
      }

      // ---- bias + mu_k (muks LDS) + mask + row max ----
      float smax = -3.0e38f;
#pragma unroll
      for (int kt = 0; kt < 4; ++kt) {
        const f32x4 mk = *(const f32x4*)&muks[k0 + kt*16 + 4*g];
        const f32x4 bv = bvq[kt];
        int ki0 = k0 + kt*16 + 4*g - R_;
        bool mq = (ki0 < 1024);
        f32x4 s = sc[kt];
#pragma unroll
        for (int r = 0; r < 4; ++r) {
          float val = s[r] + (muq_c + mk[r]) * bv[3-r];
          val = mq ? val : -3.0e38f;
          s[r] = val;
          smax = fmaxf(smax, val);
        }
        sc[kt] = s;
      }
      smax = fmaxf(smax, __shfl_xor(smax, 16));
      smax = fmaxf(smax, __shfl_xor(smax, 32));

      // ---- defer-rescale: lane-local (O^T cols = q = c) ----
      if (__any(smax > mrun)) {
        float mnew = fmaxf(mrun, smax);
        float corr = exp2_fast(mrun - mnew);
        lrun *= corr;
#pragma unroll
        for (int dt = 0; dt < 4; ++dt)
#pragma unroll
          for (int r = 0; r < 4; ++r) O[dt][r] *= corr;
        mrun = mnew;
      }

      float psum = 0.f;
#pragma unroll
      for (int kt = 0; kt < 4; ++kt)
#pragma unroll
        for (int r = 0; r < 4; ++r) {
          float pv = exp2_fast(sc[kt][r] - mrun);
          sc[kt][r] = pv;
          psum += pv;
        }
      psum += __shfl_xor(psum, 16);
      psum += __shfl_xor(psum, 32);
      lrun += psum;

      // ---- P fragments in-register (pi k-map, r14-verified) ----
      u32x4 pa[2];
#pragma unroll
      for (int kh = 0; kh < 2; ++kh) {
        pa[kh][0] = pkbf(sc[2*kh][0],   sc[2*kh][1]);
        pa[kh][1] = pkbf(sc[2*kh][2],   sc[2*kh][3]);
        pa[kh][2] = pkbf(sc[2*kh+1][0], sc[2*kh+1][1]);
        pa[kh][3] = pkbf(sc[2*kh+1][2], sc[2*kh+1][3]);
      }

      // ---- PV: O^T += V' x P (V' image pre-permuted to pi order) ----
#pragma unroll
      for (int kh = 0; kh < 2; ++kh) {
        bf16x8 pfr = __builtin_bit_cast(bf16x8, pa[kh]);
        int sw = (c & 7) << 3;
#pragma unroll
        for (int dt = 0; dt < 4; ++dt) {
          int d = dt*16 + c;
          bf16x8 va = *(const bf16x8*)&Vl[d*64 + ((32*kh + 8*g) ^ sw)];
          O[dt] = __builtin_amdgcn_mfma_f32_16x16x32_bf16(va, pfr, O[dt], 0, 0, 0);
        }
      }
    }
  }

  // ---- merge the two pipes via LDS (identical lane layouts) ----
  __syncthreads();                         // all tile LDS reads done; reuse KV
  float* sh = (float*)&KV[0][0][0];        // 4 wq x 64 lanes x 18 f32 = 18 KB
  const int base = (wq*64 + lane)*18;
  if (wp == 1) {
#pragma unroll
    for (int dt = 0; dt < 4; ++dt)
#pragma unroll
      for (int r = 0; r < 4; ++r) sh[base + dt*4 + r] = O[dt][r];
    sh[base + 16] = mrun;
    sh[base + 17] = lrun;
  }
  __syncthreads();
  if (wp == 0) {
    float m1 = sh[base + 16], l1 = sh[base + 17];
    float M  = fmaxf(mrun, m1);
    float w0 = exp2_fast(mrun - M), w1 = exp2_fast(m1 - M);
    float rl = 1.f / (lrun*w0 + l1*w1);
    const int qo = q0 + 16*wq + c;
    if (qo < N_) {
      float* ob = outg + ((size_t)bh*N_ + qo)*64;
#pragma unroll
      for (int dt = 0; dt < 4; ++dt) {
        f32x4 ov;
#pragma unroll
        for (int r = 0; r < 4; ++r)
          ov[r] = (O[dt][r]*w0 + sh[base + dt*4 + r]*w1) * rl;
        *(f32x4*)(ob + dt*16 + 4*g) = ov;
      }
    }
  }
}

extern "C" void kernel_launch(void* const* d_in, const int* in_sizes, int n_in,
                              void* d_out, int out_size, void* d_ws, size_t ws_size,
                              hipStream_t stream) {
  const float* q     = (const float*)d_in[0];
  const float* k     = (const float*)d_in[1];
  const float* v     = (const float*)d_in[2];
  const float* mu    = (const float*)d_in[3];
  const float* rel   = (const float*)d_in[4];
  const float* W1    = (const float*)d_in[5];
  const float* b1    = (const float*)d_in[6];
  const float* W2    = (const float*)d_in[7];
  const float* gamma = (const float*)d_in[8];
  // d_in[9] idx_table unused: index computed analytically in-kernel.

  // ws layout (proven >= 13.76 MB available in round 6)
  char* wsb = (char*)d_ws;
  float* btgf = (float*)wsb;                               // 12*3973*4 = 190,704
  float* mut  = (float*)(wsb + 190704);                    // 48*1028*4 = 197,376
  unsigned short* kvimg = (unsigned short*)(wsb + 388080); // 48*17*8192*2 = 13,369,344

  const int prep_blocks = 16 + NBH_*NT_ + (NBH_*N_ + 255)/256;  // 16+816+193
  prep_kernel<<<dim3(prep_blocks), dim3(256), 0, stream>>>(rel, W1, b1, W2, gamma,
                                                           k, v, mu, btgf, mut, kvimg);
  attn_kernel<<<dim3(NWG), dim3(512), 0, stream>>>(q, mu, btgf, mut, kvimg,
                                                   (float*)d_out);
}

// Round 17
// 59.370 us; speedup vs baseline: 1.0893x; 1.0893x over previous
//
#include <hip/hip_runtime.h>

#define B_ 4
#define H_ 12
#define N_ 1028
#define D_ 64
#define R_ 4
#define L_ 3969
#define HID_ 32
#define KBLK 64
#define NT_ 17
#define NBH_ 48
#define QBLK 128
#define NQT 9              // ceil(1028/128)
#define NWG (NBH_*NQT)     // 432 = 8*54
#define TBL 3973           // per-h bias table: 4 zero-sentinels + 3969
#define MUKP 1088          // padded muk row
#define LOG2E 1.4426950408889634f
#define SCL1 (0.125f*LOG2E)

typedef __attribute__((ext_vector_type(8)))  short bf16x8;
typedef __attribute__((ext_vector_type(4)))  float f32x4;
typedef __attribute__((ext_vector_type(2)))  unsigned int u32x2;
typedef __attribute__((ext_vector_type(4)))  unsigned int u32x4;
typedef __attribute__((address_space(3))) unsigned int lds_u32;
typedef const __attribute__((address_space(1))) unsigned int glb_u32;

__device__ __forceinline__ unsigned pkbf(float lo, float hi) {
  unsigned r;
  asm("v_cvt_pk_bf16_f32 %0, %1, %2" : "=v"(r) : "v"(lo), "v"(hi));
  return r;
}
__device__ __forceinline__ float exp2_fast(float x) {
  float r; asm("v_exp_f32 %0, %1" : "=v"(r) : "v"(x)); return r;
}
__device__ __forceinline__ float sgnlog1p(float x) {
  float t = log1pf(fabsf(x));
  return (x > 0.f) ? t : ((x < 0.f) ? -t : 0.f);
}

// ---- fused prep (r14/r15-proven): bias tables + K/V' pi-images + raw mut ----
// V' image in PV pi-order: within a 32-kc half, kc_loc -> p = 8*((kc_loc>>2)&3)
// + (kc_loc&3) + 4*(kc_loc>>4) so S^T output regs ARE the PV B-operand.
__global__ __launch_bounds__(256) void prep_kernel(
    const float* __restrict__ rel, const float* __restrict__ W1,
    const float* __restrict__ b1, const float* __restrict__ W2,
    const float* __restrict__ gammag, const float* __restrict__ kg,
    const float* __restrict__ vg, const float* __restrict__ mug,
    float* __restrict__ btgf, float* __restrict__ mut,
    unsigned short* __restrict__ kv)
{
  const int blk = blockIdx.x, tid = threadIdx.x;
  if (blk < 16) {
    if (blk == 0 && tid < 48) btgf[(tid >> 2)*TBL + (tid & 3)] = 0.f;
    int l = blk*256 + tid;
    if (l < L_) {
      float r0 = rel[2*l], r1 = rel[2*l+1];
      float hid[HID_];
#pragma unroll
      for (int j = 0; j < HID_; ++j) {
        float x = W1[2*j]*r0 + W1[2*j+1]*r1 + b1[j];
        hid[j] = 0.5f * x * (1.f + erff(x * 0.70710678118654752f));
      }
#pragma unroll
      for (int h = 0; h < H_; ++h) {
        float acc = 0.f;
#pragma unroll
        for (int j = 0; j < HID_; ++j) acc += W2[h*HID_+j]*hid[j];
        float gscl = LOG2E / (1.f + __expf(-gammag[h]));
        btgf[h*TBL + 4 + l] = gscl * acc;
      }
    }
  } else if (blk < 16 + NBH_*NT_) {
    const int idx = blk - 16;
    const int bh = idx / NT_, t = idx - bh*NT_;
    const int k0 = t * KBLK;
    const float* kb = kg + (size_t)bh*N_*D_;
    const float* vb = vg + (size_t)bh*N_*D_;
    unsigned short* Ko = kv + (size_t)idx*8192;
    unsigned short* Vo = Ko + 4096;
    // K image [kc][d ^ swz]
    const int kcb = tid >> 4, d4 = (tid & 15)*4;
#pragma unroll
    for (int i = 0; i < 4; ++i) {
      int kc = kcb + i*16;
      int kr = k0 + kc; if (kr >= N_) kr = N_-1;
      f32x4 a = *(const f32x4*)(kb + (size_t)kr*D_ + d4);
      *(u32x2*)&Ko[kc*64 + (d4 ^ ((kc & 7) << 3))] = (u32x2){pkbf(a[0],a[1]), pkbf(a[2],a[3])};
    }
    // V' image [d][pi(kc) ^ swz]
    const int vd0 = (tid >> 4)*4, vkc0 = (tid & 15)*4;
    const int loc = vkc0 & 31;
    const int p0 = 32*(vkc0 >> 5) + 8*((loc >> 2) & 3) + 4*(loc >> 4); // 4 contiguous
    f32x4 r[4];
#pragma unroll
    for (int i = 0; i < 4; ++i) {
      int kr = k0 + vkc0 + i; if (kr >= N_) kr = N_-1;
      r[i] = *(const f32x4*)(vb + (size_t)kr*D_ + vd0);
    }
#pragma unroll
    for (int j = 0; j < 4; ++j) {
      int d = vd0 + j;
      int addr = d*64 + ((p0 & 56) ^ ((d & 7) << 3)) + (p0 & 7);
      *(u32x2*)&Vo[addr] = (u32x2){pkbf(r[0][j],r[1][j]), pkbf(r[2][j],r[3][j])};
    }
  } else {
    int idx = (blk - (16 + NBH_*NT_))*256 + tid;
    if (idx < NBH_*N_) {
      int bh = idx / N_, n = idx - bh*N_;
      int b = bh / H_, h = bh - b*H_;
      mut[idx] = sgnlog1p(mug[((size_t)b*2*H_ + H_ + h)*N_ + n]);
    }
  }
}

// ---- attn: r15 datapath, occupancy push to 3 blocks/CU ----
// S^T = mfma(A=K,B=Q): D col=lane&15=q, row=4g+reg. [m89]  P in regs (pi map);
// O^T = mfma(A=V',B=P): col=q -> softmax fully lane-local.
// Changes vs r15 (48.5us, occ 29%): (1) launch_bounds(512,6) -> 24 waves/CU
// ceiling, VGPR cap ~42; (2) mu_k moved to LDS (muks) freeing the 16-reg mk4
// preload (hot loop now has ZERO vmem besides glds -> vmcnt(0) exact);
// (3) tail -inf mask hoisted to wave-uniform t==16 branch.
// LDS 53.0KB -> 3 blocks (159.7KB). Abort-read: WRITE >> 12.3MB = spill.
__global__ __launch_bounds__(512, 6) void attn_kernel(
    const float* __restrict__ qg, const float* __restrict__ mug,
    const float* __restrict__ btgf, const float* __restrict__ mut,
    const unsigned short* __restrict__ kv, float* __restrict__ outg)
{
  __shared__ __align__(16) unsigned short KV[2][8192]; // dbuf: K img 8KB | V' img 8KB
  __shared__ __align__(16) float btgs[TBL];            // 15.9 KB
  __shared__ __align__(16) float muks[MUKP];           // 4.35 KB; total 53.0 KB

  const int tid = threadIdx.x;
  const int w = tid >> 6, lane = tid & 63, g = lane >> 4, c = lane & 15;

  const int orig = blockIdx.x;
  const int wg = (orig & 7)*(NWG/8) + (orig >> 3);   // bijective: 432 % 8 == 0
  const int bh = wg / NQT;
  const int qt = wg - bh*NQT;
  const int b = bh / H_, h = bh - b*H_;
  const int q0 = qt * QBLK;

  const float* qb = qg + (size_t)bh*N_*D_;
  const unsigned short* kvb = kv + (size_t)bh*NT_*8192;

  // per-block LDS fills (once)
  {
    const float* bth = btgf + h*TBL;
    for (int i = tid; i < TBL; i += 512) btgs[i] = bth[i];
    const float* mt = mut + (size_t)bh*N_;
    for (int i = tid; i < MUKP; i += 512) muks[i] = mt[i < N_ ? i : N_-1];
  }

  // Q fragments (0.125*log2e folded): qf[ch] = Q[qrow][ch*32 + 8g .. +7]
  const int qrow = q0 + 16*w + c;
  const int qrc = qrow < N_ ? qrow : N_-1;
  bf16x8 qf[2];
#pragma unroll
  for (int ch = 0; ch < 2; ++ch) {
    const float* p = qb + (size_t)qrc*D_ + ch*32 + 8*g;
    f32x4 a0 = *(const f32x4*)p;
    f32x4 a1 = *(const f32x4*)(p + 4);
    u32x4 qw;
    qw[0] = pkbf(a0[0]*SCL1, a0[1]*SCL1); qw[1] = pkbf(a0[2]*SCL1, a0[3]*SCL1);
    qw[2] = pkbf(a1[0]*SCL1, a1[1]*SCL1); qw[3] = pkbf(a1[2]*SCL1, a1[3]*SCL1);
    qf[ch] = __builtin_bit_cast(bf16x8, qw);
  }
  const float muq_c = (qrow < N_) ? sgnlog1p(mug[((size_t)b*2*H_ + h)*N_ + qrow]) : 0.f;
  const int qi = qrow - R_;
  const bool qok = (qi >= 0) && (qrow < N_);
  const int qy = qi >> 5, qx = qi & 31;
  const int lqc = qy*63 + qx + 1988;    // +4 sentinel +1984 geometry

  // staging: 8 waves copy the 16KB (bh,t) image; wave w copies 2KB (2x1KB glds)
  auto issue = [&](int tt, int pp) {
    const char* src = (const char*)(kvb + (size_t)tt*8192) + w*2048;
    char* dst = (char*)&KV[pp][0] + w*2048;
#pragma unroll
    for (int j = 0; j < 2; ++j) {
      int o = j*1024;
      __builtin_amdgcn_global_load_lds((glb_u32*)(src + o + lane*16),
                                       (lds_u32*)(dst + o), 16, 0, 0);
    }
  };

  float mrun = -3.0e38f, lrun = 0.f;
  f32x4 O[4];
#pragma unroll
  for (int dt = 0; dt < 4; ++dt) O[dt] = (f32x4){0.f,0.f,0.f,0.f};

  issue(0, 0);

  for (int t = 0; t < NT_; ++t) {
    const int k0 = t * KBLK;
    const int p = t & 1;

    asm volatile("s_waitcnt vmcnt(0)" ::: "memory");   // this tile's glds landed
    __syncthreads();
    if (t + 1 < NT_) issue(t + 1, p ^ 1);              // only vmem in the loop

    const unsigned short* Kl = &KV[p][0];
    const unsigned short* Vl = &KV[p][4096];

    // ---- S^T: 4 kc-subtiles x 2 d-chunks ----
    f32x4 sc[4];
#pragma unroll
    for (int kt = 0; kt < 4; ++kt) {
      int row = kt*16 + c;
      int sw = (row & 7) << 3;
      bf16x8 ka0 = *(const bf16x8*)&Kl[row*64 + ((8*g) ^ sw)];
      bf16x8 ka1 = *(const bf16x8*)&Kl[row*64 + ((32 + 8*g) ^ sw)];
      f32x4 s = (f32x4){0.f,0.f,0.f,0.f};
      s = __builtin_amdgcn_mfma_f32_16x16x32_bf16(ka0, qf[0], s, 0, 0, 0);
      s = __builtin_amdgcn_mfma_f32_16x16x32_bf16(ka1, qf[1], s, 0, 0, 0);
      sc[kt] = s;
    }

    // ---- bias (btgs LDS quad) + mu_k (muks LDS quad) + row max ----
    float smax = -3.0e38f;
    if (t < NT_-1) {                                   // wave-uniform: no N-mask
#pragma unroll
      for (int kt = 0; kt < 4; ++kt) {
        const f32x4 mk = *(const f32x4*)&muks[k0 + kt*16 + 4*g];
        int ki0 = k0 + kt*16 + 4*g - R_;
        int lk = (ki0 >> 5)*63 + (ki0 & 31);
        int va = lqc - lk;
        bool okq = (ki0 >= 0) && qok;
        int basep = okq ? va : 3;                      // invalid -> zero sentinels
        f32x4 bv;                                      // bv[3-r] = bias of r
        bv[0] = btgs[basep-3]; bv[1] = btgs[basep-2];
        bv[2] = btgs[basep-1]; bv[3] = btgs[basep];
        f32x4 s = sc[kt];
#pragma unroll
        for (int r = 0; r < 4; ++r) {
          float val = s[r] + (muq_c + mk[r]) * bv[3-r];
          s[r] = val;
          smax = fmaxf(smax, val);
        }
        sc[kt] = s;
      }
    } else {                                           // tail tile: mask kglob>=N
#pragma unroll
      for (int kt = 0; kt < 4; ++kt) {
        const f32x4 mk = *(const f32x4*)&muks[k0 + kt*16 + 4*g];
        int ki0 = k0 + kt*16 + 4*g - R_;
        int lk = (ki0 >> 5)*63 + (ki0 & 31);
        int va = lqc - lk;
        bool okq = ((unsigned)ki0 < 1024u) && qok;
        int basep = okq ? va : 3;
        f32x4 bv;
        bv[0] = btgs[basep-3]; bv[1] = btgs[basep-2];
        bv[2] = btgs[basep-1]; bv[3] = btgs[basep];
        bool mq = (ki0 < 1024);
        f32x4 s = sc[kt];
#pragma unroll
        for (int r = 0; r < 4; ++r) {
          float val = s[r] + (muq_c + mk[r]) * bv[3-r];
          val = mq ? val : -3.0e38f;
          s[r] = val;
          smax = fmaxf(smax, val);
        }
        sc[kt] = s;
      }
    }
    smax = fmaxf(smax, __shfl_xor(smax, 16));
    smax = fmaxf(smax, __shfl_xor(smax, 32));

    // ---- defer-rescale: mrun/corr lane-local (O^T cols = q = c) ----
    if (__any(smax > mrun)) {
      float mnew = fmaxf(mrun, smax);
      float corr = exp2_fast(mrun - mnew);
      lrun *= corr;
#pragma unroll
      for (int dt = 0; dt < 4; ++dt)
#pragma unroll
        for (int r = 0; r < 4; ++r) O[dt][r] *= corr;
      mrun = mnew;
    }

    float psum = 0.f;
#pragma unroll
    for (int kt = 0; kt < 4; ++kt)
#pragma unroll
      for (int r = 0; r < 4; ++r) {
        float pv = exp2_fast(sc[kt][r] - mrun);
        sc[kt][r] = pv;
        psum += pv;
      }
    psum += __shfl_xor(psum, 16);
    psum += __shfl_xor(psum, 32);
    lrun += psum;

    // ---- P fragments in-register (pi k-map, r14-verified) ----
    u32x4 pa[2];
#pragma unroll
    for (int kh = 0; kh < 2; ++kh) {
      pa[kh][0] = pkbf(sc[2*kh][0],   sc[2*kh][1]);
      pa[kh][1] = pkbf(sc[2*kh][2],   sc[2*kh][3]);
      pa[kh][2] = pkbf(sc[2*kh+1][0], sc[2*kh+1][1]);
      pa[kh][3] = pkbf(sc[2*kh+1][2], sc[2*kh+1][3]);
    }

    // ---- PV: O^T += V' x P (V' image pre-permuted to pi order) ----
#pragma unroll
    for (int kh = 0; kh < 2; ++kh) {
      bf16x8 pfr = __builtin_bit_cast(bf16x8, pa[kh]);
      int sw = (c & 7) << 3;
#pragma unroll
      for (int dt = 0; dt < 4; ++dt) {
        int d = dt*16 + c;
        bf16x8 va = *(const bf16x8*)&Vl[d*64 + ((32*kh + 8*g) ^ sw)];
        O[dt] = __builtin_amdgcn_mfma_f32_16x16x32_bf16(va, pfr, O[dt], 0, 0, 0);
      }
    }
  }

  // ---- epilogue: O[dt][r] = O^T[d=dt*16+4g+r][q=c]; all lane-local ----
  float rlv = 1.f / lrun;
  const int qo = q0 + 16*w + c;
  if (qo < N_) {
    float* ob = outg + ((size_t)bh*N_ + qo)*64;
#pragma unroll
    for (int dt = 0; dt < 4; ++dt) {
      f32x4 ov;
#pragma unroll
      for (int r = 0; r < 4; ++r) ov[r] = O[dt][r] * rlv;
      *(f32x4*)(ob + dt*16 + 4*g) = ov;
    }
  }
}

extern "C" void kernel_launch(void* const* d_in, const int* in_sizes, int n_in,
                              void* d_out, int out_size, void* d_ws, size_t ws_size,
                              hipStream_t stream) {
  const float* q     = (const float*)d_in[0];
  const float* k     = (const float*)d_in[1];
  const float* v     = (const float*)d_in[2];
  const float* mu    = (const float*)d_in[3];
  const float* rel   = (const float*)d_in[4];
  const float* W1    = (const float*)d_in[5];
  const float* b1    = (const float*)d_in[6];
  const float* W2    = (const float*)d_in[7];
  const float* gamma = (const float*)d_in[8];
  // d_in[9] idx_table unused: index computed analytically in-kernel.

  // ws layout (proven >= 13.76 MB available in round 6)
  char* wsb = (char*)d_ws;
  float* btgf = (float*)wsb;                               // 12*3973*4 = 190,704
  float* mut  = (float*)(wsb + 190704);                    // 48*1028*4 = 197,376
  unsigned short* kvimg = (unsigned short*)(wsb + 388080); // 48*17*8192*2 = 13,369,344

  const int prep_blocks = 16 + NBH_*NT_ + (NBH_*N_ + 255)/256;  // 16+816+193
  prep_kernel<<<dim3(prep_blocks), dim3(256), 0, stream>>>(rel, W1, b1, W2, gamma,
                                                           k, v, mu, btgf, mut, kvimg);
  attn_kernel<<<dim3(NWG), dim3(512), 0, stream>>>(q, mu, btgf, mut, kvimg,
                                                   (float*)d_out);
}

// Round 18
// 57.236 us; speedup vs baseline: 1.1299x; 1.0373x over previous
//
#include <hip/hip_runtime.h>

#define B_ 4
#define H_ 12
#define N_ 1028
#define D_ 64
#define R_ 4
#define L_ 3969
#define HID_ 32
#define KBLK 64
#define NT_ 17
#define NBH_ 48
#define QBLK 128
#define NQT 9              // ceil(1028/128)
#define NWG (NBH_*NQT)     // 432 = 8*54
#define TBL 3973           // per-h bias table: 4 zero-sentinels + 3969
#define MUKP 1088          // padded muk row
#define LOG2E 1.4426950408889634f
#define SCL1 (0.125f*LOG2E)
#define THR_ 8.0f          // defer-max threshold (log2 domain); P bounded by 2^8

typedef __attribute__((ext_vector_type(8)))  short bf16x8;
typedef __attribute__((ext_vector_type(4)))  float f32x4;
typedef __attribute__((ext_vector_type(2)))  unsigned int u32x2;
typedef __attribute__((ext_vector_type(4)))  unsigned int u32x4;
typedef __attribute__((address_space(3))) unsigned int lds_u32;
typedef const __attribute__((address_space(1))) unsigned int glb_u32;

__device__ __forceinline__ unsigned pkbf(float lo, float hi) {
  unsigned r;
  asm("v_cvt_pk_bf16_f32 %0, %1, %2" : "=v"(r) : "v"(lo), "v"(hi));
  return r;
}
__device__ __forceinline__ float exp2_fast(float x) {
  float r; asm("v_exp_f32 %0, %1" : "=v"(r) : "v"(x)); return r;
}
__device__ __forceinline__ float sgnlog1p(float x) {
  float t = log1pf(fabsf(x));
  return (x > 0.f) ? t : ((x < 0.f) ? -t : 0.f);
}

// ---- fused prep (r14/r15-proven): bias tables + K/V' pi-images + raw mut ----
// V' image in PV pi-order: within a 32-kc half, kc_loc -> p = 8*((kc_loc>>2)&3)
// + (kc_loc&3) + 4*(kc_loc>>4) so S^T output regs ARE the PV B-operand.
__global__ __launch_bounds__(256) void prep_kernel(
    const float* __restrict__ rel, const float* __restrict__ W1,
    const float* __restrict__ b1, const float* __restrict__ W2,
    const float* __restrict__ gammag, const float* __restrict__ kg,
    const float* __restrict__ vg, const float* __restrict__ mug,
    float* __restrict__ btgf, float* __restrict__ mut,
    unsigned short* __restrict__ kv)
{
  const int blk = blockIdx.x, tid = threadIdx.x;
  if (blk < 16) {
    if (blk == 0 && tid < 48) btgf[(tid >> 2)*TBL + (tid & 3)] = 0.f;
    int l = blk*256 + tid;
    if (l < L_) {
      float r0 = rel[2*l], r1 = rel[2*l+1];
      float hid[HID_];
#pragma unroll
      for (int j = 0; j < HID_; ++j) {
        float x = W1[2*j]*r0 + W1[2*j+1]*r1 + b1[j];
        hid[j] = 0.5f * x * (1.f + erff(x * 0.70710678118654752f));
      }
#pragma unroll
      for (int h = 0; h < H_; ++h) {
        float acc = 0.f;
#pragma unroll
        for (int j = 0; j < HID_; ++j) acc += W2[h*HID_+j]*hid[j];
        float gscl = LOG2E / (1.f + __expf(-gammag[h]));
        btgf[h*TBL + 4 + l] = gscl * acc;
      }
    }
  } else if (blk < 16 + NBH_*NT_) {
    const int idx = blk - 16;
    const int bh = idx / NT_, t = idx - bh*NT_;
    const int k0 = t * KBLK;
    const float* kb = kg + (size_t)bh*N_*D_;
    const float* vb = vg + (size_t)bh*N_*D_;
    unsigned short* Ko = kv + (size_t)idx*8192;
    unsigned short* Vo = Ko + 4096;
    // K image [kc][d ^ swz]
    const int kcb = tid >> 4, d4 = (tid & 15)*4;
#pragma unroll
    for (int i = 0; i < 4; ++i) {
      int kc = kcb + i*16;
      int kr = k0 + kc; if (kr >= N_) kr = N_-1;
      f32x4 a = *(const f32x4*)(kb + (size_t)kr*D_ + d4);
      *(u32x2*)&Ko[kc*64 + (d4 ^ ((kc & 7) << 3))] = (u32x2){pkbf(a[0],a[1]), pkbf(a[2],a[3])};
    }
    // V' image [d][pi(kc) ^ swz]
    const int vd0 = (tid >> 4)*4, vkc0 = (tid & 15)*4;
    const int loc = vkc0 & 31;
    const int p0 = 32*(vkc0 >> 5) + 8*((loc >> 2) & 3) + 4*(loc >> 4); // 4 contiguous
    f32x4 r[4];
#pragma unroll
    for (int i = 0; i < 4; ++i) {
      int kr = k0 + vkc0 + i; if (kr >= N_) kr = N_-1;
      r[i] = *(const f32x4*)(vb + (size_t)kr*D_ + vd0);
    }
#pragma unroll
    for (int j = 0; j < 4; ++j) {
      int d = vd0 + j;
      int addr = d*64 + ((p0 & 56) ^ ((d & 7) << 3)) + (p0 & 7);
      *(u32x2*)&Vo[addr] = (u32x2){pkbf(r[0][j],r[1][j]), pkbf(r[2][j],r[3][j])};
    }
  } else {
    int idx = (blk - (16 + NBH_*NT_))*256 + tid;
    if (idx < NBH_*N_) {
      int bh = idx / N_, n = idx - bh*N_;
      int b = bh / H_, h = bh - b*H_;
      mut[idx] = sgnlog1p(mug[((size_t)b*2*H_ + H_ + h)*N_ + n]);
    }
  }
}

// ---- attn: r17 structure + T5 setprio + T13 defer-max(THR=8) ----
// S^T = mfma(A=K,B=Q): D col=lane&15=q, row=4g+reg. [m89]  P in regs (pi map);
// O^T = mfma(A=V',B=P): col=q -> softmax fully lane-local.
// (512,6): VGPR cap 42 (r17 measured 40, no spill). LDS 53KB.
__global__ __launch_bounds__(512, 6) void attn_kernel(
    const float* __restrict__ qg, const float* __restrict__ mug,
    const float* __restrict__ btgf, const float* __restrict__ mut,
    const unsigned short* __restrict__ kv, float* __restrict__ outg)
{
  __shared__ __align__(16) unsigned short KV[2][8192]; // dbuf: K img 8KB | V' img 8KB
  __shared__ __align__(16) float btgs[TBL];            // 15.9 KB
  __shared__ __align__(16) float muks[MUKP];           // 4.35 KB; total 53.0 KB

  const int tid = threadIdx.x;
  const int w = tid >> 6, lane = tid & 63, g = lane >> 4, c = lane & 15;

  const int orig = blockIdx.x;
  const int wg = (orig & 7)*(NWG/8) + (orig >> 3);   // bijective: 432 % 8 == 0
  const int bh = wg / NQT;
  const int qt = wg - bh*NQT;
  const int b = bh / H_, h = bh - b*H_;
  const int q0 = qt * QBLK;

  const float* qb = qg + (size_t)bh*N_*D_;
  const unsigned short* kvb = kv + (size_t)bh*NT_*8192;

  // per-block LDS fills (once)
  {
    const float* bth = btgf + h*TBL;
    for (int i = tid; i < TBL; i += 512) btgs[i] = bth[i];
    const float* mt = mut + (size_t)bh*N_;
    for (int i = tid; i < MUKP; i += 512) muks[i] = mt[i < N_ ? i : N_-1];
  }

  // Q fragments (0.125*log2e folded): qf[ch] = Q[qrow][ch*32 + 8g .. +7]
  const int qrow = q0 + 16*w + c;
  const int qrc = qrow < N_ ? qrow : N_-1;
  bf16x8 qf[2];
#pragma unroll
  for (int ch = 0; ch < 2; ++ch) {
    const float* p = qb + (size_t)qrc*D_ + ch*32 + 8*g;
    f32x4 a0 = *(const f32x4*)p;
    f32x4 a1 = *(const f32x4*)(p + 4);
    u32x4 qw;
    qw[0] = pkbf(a0[0]*SCL1, a0[1]*SCL1); qw[1] = pkbf(a0[2]*SCL1, a0[3]*SCL1);
    qw[2] = pkbf(a1[0]*SCL1, a1[1]*SCL1); qw[3] = pkbf(a1[2]*SCL1, a1[3]*SCL1);
    qf[ch] = __builtin_bit_cast(bf16x8, qw);
  }
  const float muq_c = (qrow < N_) ? sgnlog1p(mug[((size_t)b*2*H_ + h)*N_ + qrow]) : 0.f;
  const int qi = qrow - R_;
  const bool qok = (qi >= 0) && (qrow < N_);
  const int qy = qi >> 5, qx = qi & 31;
  const int lqc = qy*63 + qx + 1988;    // +4 sentinel +1984 geometry

  // staging: 8 waves copy the 16KB (bh,t) image; wave w copies 2KB (2x1KB glds)
  auto issue = [&](int tt, int pp) {
    const char* src = (const char*)(kvb + (size_t)tt*8192) + w*2048;
    char* dst = (char*)&KV[pp][0] + w*2048;
#pragma unroll
    for (int j = 0; j < 2; ++j) {
      int o = j*1024;
      __builtin_amdgcn_global_load_lds((glb_u32*)(src + o + lane*16),
                                       (lds_u32*)(dst + o), 16, 0, 0);
    }
  };

  float mrun = -3.0e38f, lrun = 0.f;
  f32x4 O[4];
#pragma unroll
  for (int dt = 0; dt < 4; ++dt) O[dt] = (f32x4){0.f,0.f,0.f,0.f};

  issue(0, 0);

  for (int t = 0; t < NT_; ++t) {
    const int k0 = t * KBLK;
    const int p = t & 1;

    asm volatile("s_waitcnt vmcnt(0)" ::: "memory");   // this tile's glds landed
    __syncthreads();
    if (t + 1 < NT_) issue(t + 1, p ^ 1);              // only vmem in the loop

    const unsigned short* Kl = &KV[p][0];
    const unsigned short* Vl = &KV[p][4096];

    // ---- S^T: 4 kc-subtiles x 2 d-chunks (T5: boost MFMA wave) ----
    f32x4 sc[4];
    __builtin_amdgcn_s_setprio(1);
#pragma unroll
    for (int kt = 0; kt < 4; ++kt) {
      int row = kt*16 + c;
      int sw = (row & 7) << 3;
      bf16x8 ka0 = *(const bf16x8*)&Kl[row*64 + ((8*g) ^ sw)];
      bf16x8 ka1 = *(const bf16x8*)&Kl[row*64 + ((32 + 8*g) ^ sw)];
      f32x4 s = (f32x4){0.f,0.f,0.f,0.f};
      s = __builtin_amdgcn_mfma_f32_16x16x32_bf16(ka0, qf[0], s, 0, 0, 0);
      s = __builtin_amdgcn_mfma_f32_16x16x32_bf16(ka1, qf[1], s, 0, 0, 0);
      sc[kt] = s;
    }
    __builtin_amdgcn_s_setprio(0);

    // ---- bias (btgs LDS quad) + mu_k (muks LDS quad) + row max ----
    float smax = -3.0e38f;
    if (t < NT_-1) {                                   // wave-uniform: no N-mask
#pragma unroll
      for (int kt = 0; kt < 4; ++kt) {
        const f32x4 mk = *(const f32x4*)&muks[k0 + kt*16 + 4*g];
        int ki0 = k0 + kt*16 + 4*g - R_;
        int lk = (ki0 >> 5)*63 + (ki0 & 31);
        int va = lqc - lk;
        bool okq = (ki0 >= 0) && qok;
        int basep = okq ? va : 3;                      // invalid -> zero sentinels
        f32x4 bv;                                      // bv[3-r] = bias of r
        bv[0] = btgs[basep-3]; bv[1] = btgs[basep-2];
        bv[2] = btgs[basep-1]; bv[3] = btgs[basep];
        f32x4 s = sc[kt];
#pragma unroll
        for (int r = 0; r < 4; ++r) {
          float val = s[r] + (muq_c + mk[r]) * bv[3-r];
          s[r] = val;
          smax = fmaxf(smax, val);
        }
        sc[kt] = s;
      }
    } else {                                           // tail tile: mask kglob>=N
#pragma unroll
      for (int kt = 0; kt < 4; ++kt) {
        const f32x4 mk = *(const f32x4*)&muks[k0 + kt*16 + 4*g];
        int ki0 = k0 + kt*16 + 4*g - R_;
        int lk = (ki0 >> 5)*63 + (ki0 & 31);
        int va = lqc - lk;
        bool okq = ((unsigned)ki0 < 1024u) && qok;
        int basep = okq ? va : 3;
        f32x4 bv;
        bv[0] = btgs[basep-3]; bv[1] = btgs[basep-2];
        bv[2] = btgs[basep-1]; bv[3] = btgs[basep];
        bool mq = (ki0 < 1024);
        f32x4 s = sc[kt];
#pragma unroll
        for (int r = 0; r < 4; ++r) {
          float val = s[r] + (muq_c + mk[r]) * bv[3-r];
          val = mq ? val : -3.0e38f;
          s[r] = val;
          smax = fmaxf(smax, val);
        }
        sc[kt] = s;
      }
    }
    smax = fmaxf(smax, __shfl_xor(smax, 16));
    smax = fmaxf(smax, __shfl_xor(smax, 32));

    // ---- T13 defer-max: rescale only when max grows by > THR (log2 domain).
    //      P bounded by 2^THR=256; bf16 rel-precision scale-invariant; lrun f32.
    if (__any(smax > mrun + THR_)) {
      float mnew = fmaxf(mrun, smax);
      float corr = exp2_fast(mrun - mnew);
      lrun *= corr;
#pragma unroll
      for (int dt = 0; dt < 4; ++dt)
#pragma unroll
        for (int r = 0; r < 4; ++r) O[dt][r] *= corr;
      mrun = mnew;
    }

    float psum = 0.f;
#pragma unroll
    for (int kt = 0; kt < 4; ++kt)
#pragma unroll
      for (int r = 0; r < 4; ++r) {
        float pv = exp2_fast(sc[kt][r] - mrun);
        sc[kt][r] = pv;
        psum += pv;
      }
    psum += __shfl_xor(psum, 16);
    psum += __shfl_xor(psum, 32);
    lrun += psum;

    // ---- P fragments in-register (pi k-map, r14-verified) ----
    u32x4 pa[2];
#pragma unroll
    for (int kh = 0; kh < 2; ++kh) {
      pa[kh][0] = pkbf(sc[2*kh][0],   sc[2*kh][1]);
      pa[kh][1] = pkbf(sc[2*kh][2],   sc[2*kh][3]);
      pa[kh][2] = pkbf(sc[2*kh+1][0], sc[2*kh+1][1]);
      pa[kh][3] = pkbf(sc[2*kh+1][2], sc[2*kh+1][3]);
    }

    // ---- PV: O^T += V' x P (T5: boost MFMA wave) ----
    __builtin_amdgcn_s_setprio(1);
#pragma unroll
    for (int kh = 0; kh < 2; ++kh) {
      bf16x8 pfr = __builtin_bit_cast(bf16x8, pa[kh]);
      int sw = (c & 7) << 3;
#pragma unroll
      for (int dt = 0; dt < 4; ++dt) {
        int d = dt*16 + c;
        bf16x8 va = *(const bf16x8*)&Vl[d*64 + ((32*kh + 8*g) ^ sw)];
        O[dt] = __builtin_amdgcn_mfma_f32_16x16x32_bf16(va, pfr, O[dt], 0, 0, 0);
      }
    }
    __builtin_amdgcn_s_setprio(0);
  }

  // ---- epilogue: O[dt][r] = O^T[d=dt*16+4g+r][q=c]; all lane-local ----
  float rlv = 1.f / lrun;
  const int qo = q0 + 16*w + c;
  if (qo < N_) {
    float* ob = outg + ((size_t)bh*N_ + qo)*64;
#pragma unroll
    for (int dt = 0; dt < 4; ++dt) {
      f32x4 ov;
#pragma unroll
      for (int r = 0; r < 4; ++r) ov[r] = O[dt][r] * rlv;
      *(f32x4*)(ob + dt*16 + 4*g) = ov;
    }
  }
}

extern "C" void kernel_launch(void* const* d_in, const int* in_sizes, int n_in,
                              void* d_out, int out_size, void* d_ws, size_t ws_size,
                              hipStream_t stream) {
  const float* q     = (const float*)d_in[0];
  const float* k     = (const float*)d_in[1];
  const float* v     = (const float*)d_in[2];
  const float* mu    = (const float*)d_in[3];
  const float* rel   = (const float*)d_in[4];
  const float* W1    = (const float*)d_in[5];
  const float* b1    = (const float*)d_in[6];
  const float* W2    = (const float*)d_in[7];
  const float* gamma = (const float*)d_in[8];
  // d_in[9] idx_table unused: index computed analytically in-kernel.

  // ws layout (proven >= 13.76 MB available in round 6)
  char* wsb = (char*)d_ws;
  float* btgf = (float*)wsb;                               // 12*3973*4 = 190,704
  float* mut  = (float*)(wsb + 190704);                    // 48*1028*4 = 197,376
  unsigned short* kvimg = (unsigned short*)(wsb + 388080); // 48*17*8192*2 = 13,369,344

  const int prep_blocks = 16 + NBH_*NT_ + (NBH_*N_ + 255)/256;  // 16+816+193
  prep_kernel<<<dim3(prep_blocks), dim3(256), 0, stream>>>(rel, W1, b1, W2, gamma,
                                                           k, v, mu, btgf, mut, kvimg);
  attn_kernel<<<dim3(NWG), dim3(512), 0, stream>>>(q, mu, btgf, mut, kvimg,
                                                   (float*)d_out);
}

// Round 19
// 56.111 us; speedup vs baseline: 1.1525x; 1.0200x over previous
//
#include <hip/hip_runtime.h>

#define B_ 4
#define H_ 12
#define N_ 1028
#define D_ 64
#define R_ 4
#define L_ 3969
#define HID_ 32
#define KBLK 64
#define NT_ 17
#define NBH_ 48
#define QBLK 128
#define NQT 9              // ceil(1028/128)
#define NWG (NBH_*NQT)     // 432 = 8*54
#define TBL 3973           // per-h bias table: 4 zero-sentinels + 3969
#define MUKP 1088          // padded muk row
#define LOG2E 1.4426950408889634f
#define SCL1 (0.125f*LOG2E)
#define THR_ 8.0f          // defer-max threshold (log2 domain); P bounded by 2^8

typedef __attribute__((ext_vector_type(8)))  short bf16x8;
typedef __attribute__((ext_vector_type(4)))  float f32x4;
typedef __attribute__((ext_vector_type(2)))  unsigned int u32x2;
typedef __attribute__((ext_vector_type(4)))  unsigned int u32x4;
typedef __attribute__((address_space(3))) unsigned int lds_u32;
typedef const __attribute__((address_space(1))) unsigned int glb_u32;

__device__ __forceinline__ unsigned pkbf(float lo, float hi) {
  unsigned r;
  asm("v_cvt_pk_bf16_f32 %0, %1, %2" : "=v"(r) : "v"(lo), "v"(hi));
  return r;
}
__device__ __forceinline__ float exp2_fast(float x) {
  float r; asm("v_exp_f32 %0, %1" : "=v"(r) : "v"(x)); return r;
}
__device__ __forceinline__ float sgnlog1p(float x) {
  float t = log1pf(fabsf(x));
  return (x > 0.f) ? t : ((x < 0.f) ? -t : 0.f);
}

// ---- fused prep (r14/r15-proven): bias tables + K/V' pi-images + raw mut ----
// V' image in PV pi-order: within a 32-kc half, kc_loc -> p = 8*((kc_loc>>2)&3)
// + (kc_loc&3) + 4*(kc_loc>>4) so S^T output regs ARE the PV B-operand.
__global__ __launch_bounds__(256) void prep_kernel(
    const float* __restrict__ rel, const float* __restrict__ W1,
    const float* __restrict__ b1, const float* __restrict__ W2,
    const float* __restrict__ gammag, const float* __restrict__ kg,
    const float* __restrict__ vg, const float* __restrict__ mug,
    float* __restrict__ btgf, float* __restrict__ mut,
    unsigned short* __restrict__ kv)
{
  const int blk = blockIdx.x, tid = threadIdx.x;
  if (blk < 16) {
    if (blk == 0 && tid < 48) btgf[(tid >> 2)*TBL + (tid & 3)] = 0.f;
    int l = blk*256 + tid;
    if (l < L_) {
      float r0 = rel[2*l], r1 = rel[2*l+1];
      float hid[HID_];
#pragma unroll
      for (int j = 0; j < HID_; ++j) {
        float x = W1[2*j]*r0 + W1[2*j+1]*r1 + b1[j];
        hid[j] = 0.5f * x * (1.f + erff(x * 0.70710678118654752f));
      }
#pragma unroll
      for (int h = 0; h < H_; ++h) {
        float acc = 0.f;
#pragma unroll
        for (int j = 0; j < HID_; ++j) acc += W2[h*HID_+j]*hid[j];
        float gscl = LOG2E / (1.f + __expf(-gammag[h]));
        btgf[h*TBL + 4 + l] = gscl * acc;
      }
    }
  } else if (blk < 16 + NBH_*NT_) {
    const int idx = blk - 16;
    const int bh = idx / NT_, t = idx - bh*NT_;
    const int k0 = t * KBLK;
    const float* kb = kg + (size_t)bh*N_*D_;
    const float* vb = vg + (size_t)bh*N_*D_;
    unsigned short* Ko = kv + (size_t)idx*8192;
    unsigned short* Vo = Ko + 4096;
    // K image [kc][d ^ swz]
    const int kcb = tid >> 4, d4 = (tid & 15)*4;
#pragma unroll
    for (int i = 0; i < 4; ++i) {
      int kc = kcb + i*16;
      int kr = k0 + kc; if (kr >= N_) kr = N_-1;
      f32x4 a = *(const f32x4*)(kb + (size_t)kr*D_ + d4);
      *(u32x2*)&Ko[kc*64 + (d4 ^ ((kc & 7) << 3))] = (u32x2){pkbf(a[0],a[1]), pkbf(a[2],a[3])};
    }
    // V' image [d][pi(kc) ^ swz]
    const int vd0 = (tid >> 4)*4, vkc0 = (tid & 15)*4;
    const int loc = vkc0 & 31;
    const int p0 = 32*(vkc0 >> 5) + 8*((loc >> 2) & 3) + 4*(loc >> 4); // 4 contiguous
    f32x4 r[4];
#pragma unroll
    for (int i = 0; i < 4; ++i) {
      int kr = k0 + vkc0 + i; if (kr >= N_) kr = N_-1;
      r[i] = *(const f32x4*)(vb + (size_t)kr*D_ + vd0);
    }
#pragma unroll
    for (int j = 0; j < 4; ++j) {
      int d = vd0 + j;
      int addr = d*64 + ((p0 & 56) ^ ((d & 7) << 3)) + (p0 & 7);
      *(u32x2*)&Vo[addr] = (u32x2){pkbf(r[0][j],r[1][j]), pkbf(r[2][j],r[3][j])};
    }
  } else {
    int idx = (blk - (16 + NBH_*NT_))*256 + tid;
    if (idx < NBH_*N_) {
      int bh = idx / N_, n = idx - bh*N_;
      int b = bh / H_, h = bh - b*H_;
      mut[idx] = sgnlog1p(mug[((size_t)b*2*H_ + H_ + h)*N_ + n]);
    }
  }
}

// ---- attn: r18 + deferred-psum + incremental bias index ----
// S^T = mfma(A=K,B=Q): D col=lane&15=q, row=4g+reg. [m89]  P in regs (pi map);
// O^T = mfma(A=V',B=P): col=q -> softmax fully lane-local.
// lk(t) = lk(0) + 126t exactly -> va[kt] -= 126/tile replaces per-kt index math.
// psum reduction deferred to epilogue (4 lanes/q track identical mrun -> partial
// lrun scales identically; one butterfly at end replaces 2 shfls/tile).
// (512,4): occupancy is GRID-bound (13.5 waves/CU) so the 64-VGPR budget is free.
__global__ __launch_bounds__(512, 4) void attn_kernel(
    const float* __restrict__ qg, const float* __restrict__ mug,
    const float* __restrict__ btgf, const float* __restrict__ mut,
    const unsigned short* __restrict__ kv, float* __restrict__ outg)
{
  __shared__ __align__(16) unsigned short KV[2][8192]; // dbuf: K img 8KB | V' img 8KB
  __shared__ __align__(16) float btgs[TBL];            // 15.9 KB
  __shared__ __align__(16) float muks[MUKP];           // 4.35 KB; total 53.0 KB

  const int tid = threadIdx.x;
  const int w = tid >> 6, lane = tid & 63, g = lane >> 4, c = lane & 15;

  const int orig = blockIdx.x;
  const int wg = (orig & 7)*(NWG/8) + (orig >> 3);   // bijective: 432 % 8 == 0
  const int bh = wg / NQT;
  const int qt = wg - bh*NQT;
  const int b = bh / H_, h = bh - b*H_;
  const int q0 = qt * QBLK;

  const float* qb = qg + (size_t)bh*N_*D_;
  const unsigned short* kvb = kv + (size_t)bh*NT_*8192;

  // per-block LDS fills (once)
  {
    const float* bth = btgf + h*TBL;
    for (int i = tid; i < TBL; i += 512) btgs[i] = bth[i];
    const float* mt = mut + (size_t)bh*N_;
    for (int i = tid; i < MUKP; i += 512) muks[i] = mt[i < N_ ? i : N_-1];
  }

  // Q fragments (0.125*log2e folded): qf[ch] = Q[qrow][ch*32 + 8g .. +7]
  const int qrow = q0 + 16*w + c;
  const int qrc = qrow < N_ ? qrow : N_-1;
  bf16x8 qf[2];
#pragma unroll
  for (int ch = 0; ch < 2; ++ch) {
    const float* p = qb + (size_t)qrc*D_ + ch*32 + 8*g;
    f32x4 a0 = *(const f32x4*)p;
    f32x4 a1 = *(const f32x4*)(p + 4);
    u32x4 qw;
    qw[0] = pkbf(a0[0]*SCL1, a0[1]*SCL1); qw[1] = pkbf(a0[2]*SCL1, a0[3]*SCL1);
    qw[2] = pkbf(a1[0]*SCL1, a1[1]*SCL1); qw[3] = pkbf(a1[2]*SCL1, a1[3]*SCL1);
    qf[ch] = __builtin_bit_cast(bf16x8, qw);
  }
  const float muq_c = (qrow < N_) ? sgnlog1p(mug[((size_t)b*2*H_ + h)*N_ + qrow]) : 0.f;
  const int qi = qrow - R_;
  const bool qok = (qi >= 0) && (qrow < N_);
  const int qy = qi >> 5, qx = qi & 31;
  const int lqc = qy*63 + qx + 1988;    // +4 sentinel +1984 geometry

  // incremental bias-table positions: va[kt](t) = va_init[kt] - 126*t (exact)
  int va[4];
#pragma unroll
  for (int kt = 0; kt < 4; ++kt) {
    int ki0 = kt*16 + 4*g - R_;                      // t=0 value (may be <0: unused then)
    int lk  = (ki0 >> 5)*63 + (ki0 & 31);
    va[kt]  = lqc - lk;
  }

  // staging: 8 waves copy the 16KB (bh,t) image; wave w copies 2KB (2x1KB glds)
  auto issue = [&](int tt, int pp) {
    const char* src = (const char*)(kvb + (size_t)tt*8192) + w*2048;
    char* dst = (char*)&KV[pp][0] + w*2048;
#pragma unroll
    for (int j = 0; j < 2; ++j) {
      int o = j*1024;
      __builtin_amdgcn_global_load_lds((glb_u32*)(src + o + lane*16),
                                       (lds_u32*)(dst + o), 16, 0, 0);
    }
  };

  float mrun = -3.0e38f, lrun = 0.f;   // lrun = per-lane PARTIAL (reduced in epilogue)
  f32x4 O[4];
#pragma unroll
  for (int dt = 0; dt < 4; ++dt) O[dt] = (f32x4){0.f,0.f,0.f,0.f};

  issue(0, 0);

  for (int t = 0; t < NT_; ++t) {
    const int k0 = t * KBLK;
    const int p = t & 1;

    asm volatile("s_waitcnt vmcnt(0)" ::: "memory");   // this tile's glds landed
    __syncthreads();
    if (t + 1 < NT_) issue(t + 1, p ^ 1);              // only vmem in the loop

    const unsigned short* Kl = &KV[p][0];
    const unsigned short* Vl = &KV[p][4096];

    // ---- S^T: 4 kc-subtiles x 2 d-chunks (T5: boost MFMA wave) ----
    f32x4 sc[4];
    __builtin_amdgcn_s_setprio(1);
#pragma unroll
    for (int kt = 0; kt < 4; ++kt) {
      int row = kt*16 + c;
      int sw = (row & 7) << 3;
      bf16x8 ka0 = *(const bf16x8*)&Kl[row*64 + ((8*g) ^ sw)];
      bf16x8 ka1 = *(const bf16x8*)&Kl[row*64 + ((32 + 8*g) ^ sw)];
      f32x4 s = (f32x4){0.f,0.f,0.f,0.f};
      s = __builtin_amdgcn_mfma_f32_16x16x32_bf16(ka0, qf[0], s, 0, 0, 0);
      s = __builtin_amdgcn_mfma_f32_16x16x32_bf16(ka1, qf[1], s, 0, 0, 0);
      sc[kt] = s;
    }
    __builtin_amdgcn_s_setprio(0);

    // ---- bias (incremental va) + mu_k + row max ----
    float smax = -3.0e38f;
    if (t == 0) {                                      // first tile: ki0<0 guard
#pragma unroll
      for (int kt = 0; kt < 4; ++kt) {
        const f32x4 mk = *(const f32x4*)&muks[kt*16 + 4*g];
        bool okq = qok && (kt > 0 || g > 0);           // ki0>=0 iff kt>0||g>0
        int basep = okq ? va[kt] : 3;
        f32x4 bv;
        bv[0] = btgs[basep-3]; bv[1] = btgs[basep-2];
        bv[2] = btgs[basep-1]; bv[3] = btgs[basep];
        f32x4 s = sc[kt];
#pragma unroll
        for (int r = 0; r < 4; ++r) {
          float val = s[r] + (muq_c + mk[r]) * bv[3-r];
          s[r] = val;
          smax = fmaxf(smax, val);
        }
        sc[kt] = s;
      }
    } else if (t < NT_-1) {                            // middle: okq = qok only
#pragma unroll
      for (int kt = 0; kt < 4; ++kt) {
        const f32x4 mk = *(const f32x4*)&muks[k0 + kt*16 + 4*g];
        int basep = qok ? va[kt] : 3;
        f32x4 bv;
        bv[0] = btgs[basep-3]; bv[1] = btgs[basep-2];
        bv[2] = btgs[basep-1]; bv[3] = btgs[basep];
        f32x4 s = sc[kt];
#pragma unroll
        for (int r = 0; r < 4; ++r) {
          float val = s[r] + (muq_c + mk[r]) * bv[3-r];
          s[r] = val;
          smax = fmaxf(smax, val);
        }
        sc[kt] = s;
      }
    } else {                                           // tail: mask kglob>=N
#pragma unroll
      for (int kt = 0; kt < 4; ++kt) {
        const f32x4 mk = *(const f32x4*)&muks[k0 + kt*16 + 4*g];
        int ki0 = k0 + kt*16 + 4*g - R_;
        bool mq = (ki0 < 1024);                        // only kt==0,g==0 valid
        bool okq = mq && qok;
        int basep = okq ? va[kt] : 3;
        f32x4 bv;
        bv[0] = btgs[basep-3]; bv[1] = btgs[basep-2];
        bv[2] = btgs[basep-1]; bv[3] = btgs[basep];
        f32x4 s = sc[kt];
#pragma unroll
        for (int r = 0; r < 4; ++r) {
          float val = s[r] + (muq_c + mk[r]) * bv[3-r];
          val = mq ? val : -3.0e38f;
          s[r] = val;
          smax = fmaxf(smax, val);
        }
        sc[kt] = s;
      }
    }
#pragma unroll
    for (int kt = 0; kt < 4; ++kt) va[kt] -= 126;      // exact: lk(t+1)=lk(t)+126
    smax = fmaxf(smax, __shfl_xor(smax, 16));
    smax = fmaxf(smax, __shfl_xor(smax, 32));

    // ---- T13 defer-max: rescale only when max grows by > THR ----
    if (__any(smax > mrun + THR_)) {
      float mnew = fmaxf(mrun, smax);
      float corr = exp2_fast(mrun - mnew);
      lrun *= corr;                                    // partial scales identically
#pragma unroll
      for (int dt = 0; dt < 4; ++dt)
#pragma unroll
        for (int r = 0; r < 4; ++r) O[dt][r] *= corr;
      mrun = mnew;
    }

    // ---- exp2 + PARTIAL row sum (no per-tile shfl; reduced in epilogue) ----
    float psum = 0.f;
#pragma unroll
    for (int kt = 0; kt < 4; ++kt)
#pragma unroll
      for (int r = 0; r < 4; ++r) {
        float pv = exp2_fast(sc[kt][r] - mrun);
        sc[kt][r] = pv;
        psum += pv;
      }
    lrun += psum;

    // ---- P fragments in-register (pi k-map, r14-verified) ----
    u32x4 pa[2];
#pragma unroll
    for (int kh = 0; kh < 2; ++kh) {
      pa[kh][0] = pkbf(sc[2*kh][0],   sc[2*kh][1]);
      pa[kh][1] = pkbf(sc[2*kh][2],   sc[2*kh][3]);
      pa[kh][2] = pkbf(sc[2*kh+1][0], sc[2*kh+1][1]);
      pa[kh][3] = pkbf(sc[2*kh+1][2], sc[2*kh+1][3]);
    }

    // ---- PV: O^T += V' x P (T5: boost MFMA wave) ----
    __builtin_amdgcn_s_setprio(1);
#pragma unroll
    for (int kh = 0; kh < 2; ++kh) {
      bf16x8 pfr = __builtin_bit_cast(bf16x8, pa[kh]);
      int sw = (c & 7) << 3;
#pragma unroll
      for (int dt = 0; dt < 4; ++dt) {
        int d = dt*16 + c;
        bf16x8 va2 = *(const bf16x8*)&Vl[d*64 + ((32*kh + 8*g) ^ sw)];
        O[dt] = __builtin_amdgcn_mfma_f32_16x16x32_bf16(va2, pfr, O[dt], 0, 0, 0);
      }
    }
    __builtin_amdgcn_s_setprio(0);
  }

  // ---- epilogue: reduce partial lrun across the 4 g-lanes, then store ----
  lrun += __shfl_xor(lrun, 16);
  lrun += __shfl_xor(lrun, 32);
  float rlv = 1.f / lrun;
  const int qo = q0 + 16*w + c;
  if (qo < N_) {
    float* ob = outg + ((size_t)bh*N_ + qo)*64;
#pragma unroll
    for (int dt = 0; dt < 4; ++dt) {
      f32x4 ov;
#pragma unroll
      for (int r = 0; r < 4; ++r) ov[r] = O[dt][r] * rlv;
      *(f32x4*)(ob + dt*16 + 4*g) = ov;
    }
  }
}

extern "C" void kernel_launch(void* const* d_in, const int* in_sizes, int n_in,
                              void* d_out, int out_size, void* d_ws, size_t ws_size,
                              hipStream_t stream) {
  const float* q     = (const float*)d_in[0];
  const float* k     = (const float*)d_in[1];
  const float* v     = (const float*)d_in[2];
  const float* mu    = (const float*)d_in[3];
  const float* rel   = (const float*)d_in[4];
  const float* W1    = (const float*)d_in[5];
  const float* b1    = (const float*)d_in[6];
  const float* W2    = (const float*)d_in[7];
  const float* gamma = (const float*)d_in[8];
  // d_in[9] idx_table unused: index computed analytically in-kernel.

  // ws layout (proven >= 13.76 MB available in round 6)
  char* wsb = (char*)d_ws;
  float* btgf = (float*)wsb;                               // 12*3973*4 = 190,704
  float* mut  = (float*)(wsb + 190704);                    // 48*1028*4 = 197,376
  unsigned short* kvimg = (unsigned short*)(wsb + 388080); // 48*17*8192*2 = 13,369,344

  const int prep_blocks = 16 + NBH_*NT_ + (NBH_*N_ + 255)/256;  // 16+816+193
  prep_kernel<<<dim3(prep_blocks), dim3(256), 0, stream>>>(rel, W1, b1, W2, gamma,
                                                           k, v, mu, btgf, mut, kvimg);
  attn_kernel<<<dim3(NWG), dim3(512), 0, stream>>>(q, mu, btgf, mut, kvimg,
                                                   (float*)d_out);
}